// Round 1
// baseline (1401.968 us; speedup 1.0000x reference)
//
#include <hip/hip_runtime.h>
#include <math.h>

#define NN 100000
#define NE 1600000
#define F_IN 128
#define HID 64
#define OUTF 40

// ---------------- degree ----------------
__global__ void k_deg_init(float* deg) {
    int i = blockIdx.x * blockDim.x + threadIdx.x;
    if (i < NN) deg[i] = 1.0f;  // self-loop
}

__global__ void k_deg_accum(const int* __restrict__ col, float* __restrict__ deg) {
    int stride = gridDim.x * blockDim.x;
    for (int e = blockIdx.x * blockDim.x + threadIdx.x; e < NE; e += stride)
        atomicAdd(&deg[col[e]], 1.0f);
}

__global__ void k_dinv(float* deg) {
    int i = blockIdx.x * blockDim.x + threadIdx.x;
    if (i < NN) deg[i] = rsqrtf(deg[i]);
}

// ---------------- GEMM1: h1 = x @ W1 ; agg1 = h1 * dinv^2 ----------------
__launch_bounds__(256)
__global__ void k_gemm1(const float* __restrict__ x, const float* __restrict__ W1,
                        const float* __restrict__ dinv,
                        float* __restrict__ h1, float* __restrict__ agg1) {
    __shared__ float Xs[64][132];   // 64 rows x 128 k, padded
    __shared__ float Ws[128][64];   // 128 k x 64 cols
    int t = threadIdx.x;
    int row0 = blockIdx.x * 64;

    // stage W1: 8192 floats = 2048 float4
#pragma unroll
    for (int i = 0; i < 8; i++) {
        int idx4 = t + 256 * i;
        float4 v = ((const float4*)W1)[idx4];
        int k = idx4 >> 4;
        int c4 = (idx4 & 15) << 2;
        *(float4*)&Ws[k][c4] = v;
    }
    // stage X tile: 64 rows x 128 = 2048 float4
#pragma unroll
    for (int i = 0; i < 8; i++) {
        int idx4 = t + 256 * i;
        int r = idx4 >> 5;
        int k4 = (idx4 & 31) << 2;
        int gr = row0 + r;
        if (gr >= NN) gr = NN - 1;
        float4 v = *(const float4*)&x[gr * F_IN + k4];
        *(float4*)&Xs[r][k4] = v;
    }
    __syncthreads();

    int tx = t & 15, ty = t >> 4;
    int cb = tx << 2, rb = ty << 2;
    float acc[4][4] = {};
#pragma unroll
    for (int k = 0; k < F_IN; k += 4) {
        float4 xv[4], wv[4];
#pragma unroll
        for (int i = 0; i < 4; i++) xv[i] = *(const float4*)&Xs[rb + i][k];
#pragma unroll
        for (int kk = 0; kk < 4; kk++) wv[kk] = *(const float4*)&Ws[k + kk][cb];
#pragma unroll
        for (int i = 0; i < 4; i++) {
            const float* xp = (const float*)&xv[i];
#pragma unroll
            for (int kk = 0; kk < 4; kk++) {
                acc[i][0] += xp[kk] * wv[kk].x;
                acc[i][1] += xp[kk] * wv[kk].y;
                acc[i][2] += xp[kk] * wv[kk].z;
                acc[i][3] += xp[kk] * wv[kk].w;
            }
        }
    }
#pragma unroll
    for (int i = 0; i < 4; i++) {
        int gr = row0 + rb + i;
        if (gr < NN) {
            float4 v = make_float4(acc[i][0], acc[i][1], acc[i][2], acc[i][3]);
            *(float4*)&h1[gr * HID + cb] = v;
            float d = dinv[gr];
            float s = d * d;
            float4 w = make_float4(v.x * s, v.y * s, v.z * s, v.w * s);
            *(float4*)&agg1[gr * HID + cb] = w;
        }
    }
}

// ---------------- scatter1: agg1[col] += h1[row] * dinv[row]*dinv[col] ----------------
__global__ void k_scatter1(const int* __restrict__ ei, const float* __restrict__ dinv,
                           const float* __restrict__ h1, float* __restrict__ agg1) {
    int lane = threadIdx.x & 63;
    int wid = (blockIdx.x * blockDim.x + threadIdx.x) >> 6;
    int nw = (gridDim.x * blockDim.x) >> 6;
    for (int e = wid; e < NE; e += nw) {
        int row = ei[e];
        int col = ei[NE + e];
        float norm = dinv[row] * dinv[col];
        float v = h1[row * HID + lane] * norm;
        atomicAdd(&agg1[col * HID + lane], v);
    }
}

// ---------------- GEMM2: h2 = relu(agg1+b1) @ W2 ; out = h2*dinv^2 + b2 ----------------
__launch_bounds__(320)
__global__ void k_gemm2(const float* __restrict__ agg1, const float* __restrict__ b1,
                        const float* __restrict__ W2, const float* __restrict__ b2,
                        const float* __restrict__ dinv,
                        float* __restrict__ h2, float* __restrict__ outb) {
    __shared__ float As[128][68];
    __shared__ float Ws[64][40];
    int t = threadIdx.x;
    int row0 = blockIdx.x * 128;

    for (int i = t; i < 64 * 40; i += 320) Ws[i / 40][i % 40] = W2[i];

    for (int idx4 = t; idx4 < 2048; idx4 += 320) {
        int r = idx4 >> 4, k4 = (idx4 & 15) << 2;
        int gr = row0 + r;
        if (gr >= NN) gr = NN - 1;
        float4 v = *(const float4*)&agg1[gr * HID + k4];
        float4 bb = *(const float4*)&b1[k4];
        v.x = fmaxf(v.x + bb.x, 0.f);
        v.y = fmaxf(v.y + bb.y, 0.f);
        v.z = fmaxf(v.z + bb.z, 0.f);
        v.w = fmaxf(v.w + bb.w, 0.f);
        *(float4*)&As[r][k4] = v;
    }
    __syncthreads();

    int tx = t % 10, ty = t / 10;  // ty 0..31
    int cb = tx * 4, rb = ty * 4;
    float acc[4][4] = {};
#pragma unroll
    for (int k = 0; k < HID; k += 4) {
        float4 xv[4], wv[4];
#pragma unroll
        for (int i = 0; i < 4; i++) xv[i] = *(const float4*)&As[rb + i][k];
#pragma unroll
        for (int kk = 0; kk < 4; kk++) wv[kk] = *(const float4*)&Ws[k + kk][cb];
#pragma unroll
        for (int i = 0; i < 4; i++) {
            const float* xp = (const float*)&xv[i];
#pragma unroll
            for (int kk = 0; kk < 4; kk++) {
                acc[i][0] += xp[kk] * wv[kk].x;
                acc[i][1] += xp[kk] * wv[kk].y;
                acc[i][2] += xp[kk] * wv[kk].z;
                acc[i][3] += xp[kk] * wv[kk].w;
            }
        }
    }
#pragma unroll
    for (int i = 0; i < 4; i++) {
        int gr = row0 + rb + i;
        if (gr < NN) {
            float4 hv = make_float4(acc[i][0], acc[i][1], acc[i][2], acc[i][3]);
            *(float4*)&h2[gr * OUTF + cb] = hv;
            float d = dinv[gr];
            float s = d * d;
            float4 bb = *(const float4*)&b2[cb];
            float4 ov = make_float4(hv.x * s + bb.x, hv.y * s + bb.y,
                                    hv.z * s + bb.z, hv.w * s + bb.w);
            *(float4*)&outb[gr * OUTF + cb] = ov;
        }
    }
}

// ---------------- scatter2: out[col] += h2[row] * norm ----------------
__global__ void k_scatter2(const int* __restrict__ ei, const float* __restrict__ dinv,
                           const float* __restrict__ h2, float* __restrict__ outb) {
    int lane = threadIdx.x & 63;
    int wid = (blockIdx.x * blockDim.x + threadIdx.x) >> 6;
    int nw = (gridDim.x * blockDim.x) >> 6;
    for (int e = wid; e < NE; e += nw) {
        int row = ei[e];
        int col = ei[NE + e];
        float norm = dinv[row] * dinv[col];
        if (lane < OUTF) {
            float v = h2[row * OUTF + lane] * norm;
            atomicAdd(&outb[col * OUTF + lane], v);
        }
    }
}

// ---------------- log_softmax in place ----------------
__global__ void k_logsoftmax(float* __restrict__ outb) {
    int lane = threadIdx.x & 63;
    int wid = (blockIdx.x * blockDim.x + threadIdx.x) >> 6;
    if (wid >= NN) return;
    float v = (lane < OUTF) ? outb[wid * OUTF + lane] : -INFINITY;
    float m = v;
#pragma unroll
    for (int o = 32; o > 0; o >>= 1) m = fmaxf(m, __shfl_xor(m, o, 64));
    float p = (lane < OUTF) ? expf(v - m) : 0.f;
    float s = p;
#pragma unroll
    for (int o = 32; o > 0; o >>= 1) s += __shfl_xor(s, o, 64);
    float r = v - m - logf(s);
    if (lane < OUTF) outb[wid * OUTF + lane] = r;
}

extern "C" void kernel_launch(void* const* d_in, const int* in_sizes, int n_in,
                              void* d_out, int out_size, void* d_ws, size_t ws_size,
                              hipStream_t stream) {
    const float* x  = (const float*)d_in[0];
    const int*   ei = (const int*)d_in[1];
    const float* W1 = (const float*)d_in[2];
    const float* b1 = (const float*)d_in[3];
    const float* W2 = (const float*)d_in[4];
    const float* b2 = (const float*)d_in[5];
    float* outb = (float*)d_out;

    float* dinv = (float*)d_ws;             // NN
    float* h1   = dinv + NN;                // NN*64
    float* agg1 = h1 + (size_t)NN * HID;    // NN*64
    float* h2   = h1;                       // reuse (NN*40 <= NN*64)

    k_deg_init<<<(NN + 255) / 256, 256, 0, stream>>>(dinv);
    k_deg_accum<<<2048, 256, 0, stream>>>(ei + NE, dinv);
    k_dinv<<<(NN + 255) / 256, 256, 0, stream>>>(dinv);

    k_gemm1<<<(NN + 63) / 64, 256, 0, stream>>>(x, W1, dinv, h1, agg1);
    k_scatter1<<<4096, 256, 0, stream>>>(ei, dinv, h1, agg1);
    k_gemm2<<<(NN + 127) / 128, 320, 0, stream>>>(agg1, b1, W2, b2, dinv, h2, outb);
    k_scatter2<<<4096, 256, 0, stream>>>(ei, dinv, h2, outb);
    k_logsoftmax<<<(NN * 64 + 255) / 256, 256, 0, stream>>>(outb);
}

// Round 2
// 746.815 us; speedup vs baseline: 1.8773x; 1.8773x over previous
//
#include <hip/hip_runtime.h>
#include <math.h>

#define NN 100000
#define NE 1600000
#define F_IN 128
#define HID 64
#define OUTF 40

// ---------------- degree ----------------
__global__ void k_deg_init(float* deg) {
    int i = blockIdx.x * blockDim.x + threadIdx.x;
    if (i < NN) deg[i] = 1.0f;  // self-loop
}

__global__ void k_deg_accum(const int* __restrict__ col, float* __restrict__ deg) {
    int stride = gridDim.x * blockDim.x;
    for (int e = blockIdx.x * blockDim.x + threadIdx.x; e < NE; e += stride)
        atomicAdd(&deg[col[e]], 1.0f);
}

__global__ void k_dinv(float* deg) {
    int i = blockIdx.x * blockDim.x + threadIdx.x;
    if (i < NN) deg[i] = rsqrtf(deg[i]);
}

// ---------------- GEMM1: h1 = x @ W1 ; agg1 = h1 * dinv^2 ----------------
__launch_bounds__(256)
__global__ void k_gemm1(const float* __restrict__ x, const float* __restrict__ W1,
                        const float* __restrict__ dinv,
                        float* __restrict__ h1, float* __restrict__ agg1) {
    __shared__ float Xs[64][132];   // 64 rows x 128 k, padded (16B-aligned rows)
    __shared__ float Ws[128][64];   // 128 k x 64 cols
    int t = threadIdx.x;
    int row0 = blockIdx.x * 64;

    // stage W1: 8192 floats = 2048 float4
#pragma unroll
    for (int i = 0; i < 8; i++) {
        int idx4 = t + 256 * i;
        float4 v = ((const float4*)W1)[idx4];
        int k = idx4 >> 4;
        int c4 = (idx4 & 15) << 2;
        *(float4*)&Ws[k][c4] = v;
    }
    // stage X tile: 64 rows x 128 = 2048 float4
#pragma unroll
    for (int i = 0; i < 8; i++) {
        int idx4 = t + 256 * i;
        int r = idx4 >> 5;
        int k4 = (idx4 & 31) << 2;
        int gr = row0 + r;
        if (gr >= NN) gr = NN - 1;
        float4 v = *(const float4*)&x[gr * F_IN + k4];
        *(float4*)&Xs[r][k4] = v;
    }
    __syncthreads();

    int tx = t & 15, ty = t >> 4;
    int cb = tx << 2, rb = ty << 2;
    float acc[4][4] = {};
#pragma unroll 2                      // capped: full unroll spilled to scratch (R1)
    for (int k = 0; k < F_IN; k += 4) {
        float4 xv[4], wv[4];
#pragma unroll
        for (int i = 0; i < 4; i++) xv[i] = *(const float4*)&Xs[rb + i][k];
#pragma unroll
        for (int kk = 0; kk < 4; kk++) wv[kk] = *(const float4*)&Ws[k + kk][cb];
#pragma unroll
        for (int i = 0; i < 4; i++) {
            const float* xp = (const float*)&xv[i];
#pragma unroll
            for (int kk = 0; kk < 4; kk++) {
                acc[i][0] += xp[kk] * wv[kk].x;
                acc[i][1] += xp[kk] * wv[kk].y;
                acc[i][2] += xp[kk] * wv[kk].z;
                acc[i][3] += xp[kk] * wv[kk].w;
            }
        }
    }
#pragma unroll
    for (int i = 0; i < 4; i++) {
        int gr = row0 + rb + i;
        if (gr < NN) {
            float4 v = make_float4(acc[i][0], acc[i][1], acc[i][2], acc[i][3]);
            *(float4*)&h1[gr * HID + cb] = v;
            float d = dinv[gr];
            float s = d * d;
            float4 w = make_float4(v.x * s, v.y * s, v.z * s, v.w * s);
            *(float4*)&agg1[gr * HID + cb] = w;
        }
    }
}

// ---------------- scatter1: agg1[col] += h1[row] * dinv[row]*dinv[col] ----------------
__global__ void k_scatter1(const int* __restrict__ ei, const float* __restrict__ dinv,
                           const float* __restrict__ h1, float* __restrict__ agg1) {
    int lane = threadIdx.x & 63;
    int wid = (blockIdx.x * blockDim.x + threadIdx.x) >> 6;
    int nw = (gridDim.x * blockDim.x) >> 6;
    for (int e = wid; e < NE; e += nw) {
        int row = ei[e];
        int col = ei[NE + e];
        float norm = dinv[row] * dinv[col];
        float v = h1[row * HID + lane] * norm;
        atomicAdd(&agg1[col * HID + lane], v);
    }
}

// ---------------- GEMM2: h2 = relu(agg1+b1) @ W2 ; out = h2*dinv^2 + b2 ----------------
__launch_bounds__(320)
__global__ void k_gemm2(const float* __restrict__ agg1, const float* __restrict__ b1,
                        const float* __restrict__ W2, const float* __restrict__ b2,
                        const float* __restrict__ dinv,
                        float* __restrict__ h2, float* __restrict__ outb) {
    __shared__ float As[128][68];
    __shared__ float Ws[64][40];
    int t = threadIdx.x;
    int row0 = blockIdx.x * 128;

    for (int i = t; i < 64 * 40; i += 320) Ws[i / 40][i % 40] = W2[i];

    for (int idx4 = t; idx4 < 2048; idx4 += 320) {
        int r = idx4 >> 4, k4 = (idx4 & 15) << 2;
        int gr = row0 + r;
        if (gr >= NN) gr = NN - 1;
        float4 v = *(const float4*)&agg1[gr * HID + k4];
        float4 bb = *(const float4*)&b1[k4];
        v.x = fmaxf(v.x + bb.x, 0.f);
        v.y = fmaxf(v.y + bb.y, 0.f);
        v.z = fmaxf(v.z + bb.z, 0.f);
        v.w = fmaxf(v.w + bb.w, 0.f);
        *(float4*)&As[r][k4] = v;
    }
    __syncthreads();

    int tx = t % 10, ty = t / 10;  // ty 0..31
    int cb = tx * 4, rb = ty * 4;
    float acc[4][4] = {};
#pragma unroll 2                      // capped: full unroll spilled to scratch (R1)
    for (int k = 0; k < HID; k += 4) {
        float4 xv[4], wv[4];
#pragma unroll
        for (int i = 0; i < 4; i++) xv[i] = *(const float4*)&As[rb + i][k];
#pragma unroll
        for (int kk = 0; kk < 4; kk++) wv[kk] = *(const float4*)&Ws[k + kk][cb];
#pragma unroll
        for (int i = 0; i < 4; i++) {
            const float* xp = (const float*)&xv[i];
#pragma unroll
            for (int kk = 0; kk < 4; kk++) {
                acc[i][0] += xp[kk] * wv[kk].x;
                acc[i][1] += xp[kk] * wv[kk].y;
                acc[i][2] += xp[kk] * wv[kk].z;
                acc[i][3] += xp[kk] * wv[kk].w;
            }
        }
    }
#pragma unroll
    for (int i = 0; i < 4; i++) {
        int gr = row0 + rb + i;
        if (gr < NN) {
            float4 hv = make_float4(acc[i][0], acc[i][1], acc[i][2], acc[i][3]);
            *(float4*)&h2[gr * OUTF + cb] = hv;
            float d = dinv[gr];
            float s = d * d;
            float4 bb = *(const float4*)&b2[cb];
            float4 ov = make_float4(hv.x * s + bb.x, hv.y * s + bb.y,
                                    hv.z * s + bb.z, hv.w * s + bb.w);
            *(float4*)&outb[gr * OUTF + cb] = ov;
        }
    }
}

// ---------------- scatter2: out[col] += h2[row] * norm ----------------
__global__ void k_scatter2(const int* __restrict__ ei, const float* __restrict__ dinv,
                           const float* __restrict__ h2, float* __restrict__ outb) {
    int lane = threadIdx.x & 63;
    int wid = (blockIdx.x * blockDim.x + threadIdx.x) >> 6;
    int nw = (gridDim.x * blockDim.x) >> 6;
    for (int e = wid; e < NE; e += nw) {
        int row = ei[e];
        int col = ei[NE + e];
        float norm = dinv[row] * dinv[col];
        if (lane < OUTF) {
            float v = h2[row * OUTF + lane] * norm;
            atomicAdd(&outb[col * OUTF + lane], v);
        }
    }
}

// ---------------- log_softmax in place ----------------
__global__ void k_logsoftmax(float* __restrict__ outb) {
    int lane = threadIdx.x & 63;
    int wid = (blockIdx.x * blockDim.x + threadIdx.x) >> 6;
    if (wid >= NN) return;
    float v = (lane < OUTF) ? outb[wid * OUTF + lane] : -INFINITY;
    float m = v;
#pragma unroll
    for (int o = 32; o > 0; o >>= 1) m = fmaxf(m, __shfl_xor(m, o, 64));
    float p = (lane < OUTF) ? expf(v - m) : 0.f;
    float s = p;
#pragma unroll
    for (int o = 32; o > 0; o >>= 1) s += __shfl_xor(s, o, 64);
    float r = v - m - logf(s);
    if (lane < OUTF) outb[wid * OUTF + lane] = r;
}

extern "C" void kernel_launch(void* const* d_in, const int* in_sizes, int n_in,
                              void* d_out, int out_size, void* d_ws, size_t ws_size,
                              hipStream_t stream) {
    const float* x  = (const float*)d_in[0];
    const int*   ei = (const int*)d_in[1];
    const float* W1 = (const float*)d_in[2];
    const float* b1 = (const float*)d_in[3];
    const float* W2 = (const float*)d_in[4];
    const float* b2 = (const float*)d_in[5];
    float* outb = (float*)d_out;

    float* dinv = (float*)d_ws;             // NN
    float* h1   = dinv + NN;                // NN*64
    float* agg1 = h1 + (size_t)NN * HID;    // NN*64
    float* h2   = h1;                       // reuse (NN*40 <= NN*64)

    k_deg_init<<<(NN + 255) / 256, 256, 0, stream>>>(dinv);
    k_deg_accum<<<2048, 256, 0, stream>>>(ei + NE, dinv);
    k_dinv<<<(NN + 255) / 256, 256, 0, stream>>>(dinv);

    k_gemm1<<<(NN + 63) / 64, 256, 0, stream>>>(x, W1, dinv, h1, agg1);
    k_scatter1<<<4096, 256, 0, stream>>>(ei, dinv, h1, agg1);
    k_gemm2<<<(NN + 127) / 128, 320, 0, stream>>>(agg1, b1, W2, b2, dinv, h2, outb);
    k_scatter2<<<4096, 256, 0, stream>>>(ei, dinv, h2, outb);
    k_logsoftmax<<<(NN * 64 + 255) / 256, 256, 0, stream>>>(outb);
}

// Round 3
// 546.785 us; speedup vs baseline: 2.5640x; 1.3658x over previous
//
#include <hip/hip_runtime.h>
#include <math.h>

#define NN 100000
#define NE 1600000
#define F_IN 128
#define HID 64
#define OUTF 40
#define NB 391   // (NN+255)/256

// ---------------- CSR build ----------------
__global__ void k_zero(int* deg) {
    int i = blockIdx.x * blockDim.x + threadIdx.x;
    if (i < NN) deg[i] = 0;
}

__global__ void k_hist(const int* __restrict__ col, int* __restrict__ deg) {
    int stride = gridDim.x * blockDim.x;
    for (int e = blockIdx.x * blockDim.x + threadIdx.x; e < NE; e += stride)
        atomicAdd(&deg[col[e]], 1);
}

__global__ void k_dinv(const int* __restrict__ deg, float* __restrict__ dinv) {
    int i = blockIdx.x * blockDim.x + threadIdx.x;
    if (i < NN) dinv[i] = rsqrtf((float)(deg[i] + 1));  // +1 self-loop
}

__global__ void k_blocksum(const int* __restrict__ deg, int* __restrict__ bsum) {
    __shared__ int s[256];
    int t = threadIdx.x;
    int i = blockIdx.x * 256 + t;
    s[t] = (i < NN) ? deg[i] : 0;
    __syncthreads();
    for (int o = 128; o > 0; o >>= 1) {
        if (t < o) s[t] += s[t + o];
        __syncthreads();
    }
    if (t == 0) bsum[blockIdx.x] = s[0];
}

__global__ void k_scanbsum(int* __restrict__ bsum) {  // 1 block, 512 threads
    __shared__ int s[512];
    int t = threadIdx.x;
    int v = (t < NB) ? bsum[t] : 0;
    s[t] = v;
    __syncthreads();
    for (int o = 1; o < 512; o <<= 1) {
        int add = (t >= o) ? s[t - o] : 0;
        __syncthreads();
        s[t] += add;
        __syncthreads();
    }
    if (t < NB) bsum[t] = s[t] - v;  // exclusive
}

__global__ void k_cursor(const int* __restrict__ deg, const int* __restrict__ bsum,
                         int* __restrict__ cursor) {
    __shared__ int s[256];
    int t = threadIdx.x;
    int i = blockIdx.x * 256 + t;
    int v = (i < NN) ? deg[i] : 0;
    s[t] = v;
    __syncthreads();
    for (int o = 1; o < 256; o <<= 1) {
        int add = (t >= o) ? s[t - o] : 0;
        __syncthreads();
        s[t] += add;
        __syncthreads();
    }
    if (i < NN) cursor[i] = bsum[blockIdx.x] + s[t] - v;  // exclusive prefix = rowoff
}

__global__ void k_fill(const int* __restrict__ ei, int* __restrict__ cursor,
                       int* __restrict__ eidx) {
    int stride = gridDim.x * blockDim.x;
    for (int e = blockIdx.x * blockDim.x + threadIdx.x; e < NE; e += stride) {
        int row = ei[e];
        int col = ei[NE + e];
        int pos = atomicAdd(&cursor[col], 1);
        eidx[pos] = row;
    }
    // after this kernel: cursor[n] == rowoff[n+1]
}

// ---------------- GEMM1: h1 = x @ W1 ----------------
__launch_bounds__(256)
__global__ void k_gemm1(const float* __restrict__ x, const float* __restrict__ W1,
                        float* __restrict__ h1) {
    __shared__ float Xs[64][132];
    __shared__ float Ws[128][64];
    int t = threadIdx.x;
    int row0 = blockIdx.x * 64;

#pragma unroll
    for (int i = 0; i < 8; i++) {
        int idx4 = t + 256 * i;
        float4 v = ((const float4*)W1)[idx4];
        int k = idx4 >> 4;
        int c4 = (idx4 & 15) << 2;
        *(float4*)&Ws[k][c4] = v;
    }
#pragma unroll
    for (int i = 0; i < 8; i++) {
        int idx4 = t + 256 * i;
        int r = idx4 >> 5;
        int k4 = (idx4 & 31) << 2;
        int gr = row0 + r;
        if (gr >= NN) gr = NN - 1;
        float4 v = *(const float4*)&x[gr * F_IN + k4];
        *(float4*)&Xs[r][k4] = v;
    }
    __syncthreads();

    int tx = t & 15, ty = t >> 4;
    int cb = tx << 2, rb = ty << 2;
    float acc[4][4] = {};
#pragma unroll 2   // capped: full unroll spills (R1)
    for (int k = 0; k < F_IN; k += 4) {
        float4 xv[4], wv[4];
#pragma unroll
        for (int i = 0; i < 4; i++) xv[i] = *(const float4*)&Xs[rb + i][k];
#pragma unroll
        for (int kk = 0; kk < 4; kk++) wv[kk] = *(const float4*)&Ws[k + kk][cb];
#pragma unroll
        for (int i = 0; i < 4; i++) {
            const float* xp = (const float*)&xv[i];
#pragma unroll
            for (int kk = 0; kk < 4; kk++) {
                acc[i][0] += xp[kk] * wv[kk].x;
                acc[i][1] += xp[kk] * wv[kk].y;
                acc[i][2] += xp[kk] * wv[kk].z;
                acc[i][3] += xp[kk] * wv[kk].w;
            }
        }
    }
#pragma unroll
    for (int i = 0; i < 4; i++) {
        int gr = row0 + rb + i;
        if (gr < NN)
            *(float4*)&h1[gr * HID + cb] =
                make_float4(acc[i][0], acc[i][1], acc[i][2], acc[i][3]);
    }
}

// ---------------- agg1: gather-based aggregation, 64 feats ----------------
__global__ void k_agg1(const int* __restrict__ cursor, const int* __restrict__ eidx,
                       const float* __restrict__ dinv, const float* __restrict__ h1,
                       float* __restrict__ agg1) {
    int lane = threadIdx.x & 63;
    int n = (blockIdx.x * blockDim.x + threadIdx.x) >> 6;
    if (n >= NN) return;
    int end = cursor[n];
    int start = (n == 0) ? 0 : cursor[n - 1];
    float dn = dinv[n];
    float acc = h1[n * HID + lane] * dn * dn;  // self-loop
    for (int j = start; j < end; j++) {
        int src = eidx[j];
        float w = dinv[src] * dn;
        acc += h1[src * HID + lane] * w;
    }
    agg1[n * HID + lane] = acc;
}

// ---------------- GEMM2: h2 = relu(agg1+b1) @ W2 ----------------
__launch_bounds__(320)
__global__ void k_gemm2(const float* __restrict__ agg1, const float* __restrict__ b1,
                        const float* __restrict__ W2, float* __restrict__ h2) {
    __shared__ float As[128][68];
    __shared__ float Ws[64][40];
    int t = threadIdx.x;
    int row0 = blockIdx.x * 128;

    for (int i = t; i < 64 * 40; i += 320) Ws[i / 40][i % 40] = W2[i];

    for (int idx4 = t; idx4 < 2048; idx4 += 320) {
        int r = idx4 >> 4, k4 = (idx4 & 15) << 2;
        int gr = row0 + r;
        if (gr >= NN) gr = NN - 1;
        float4 v = *(const float4*)&agg1[gr * HID + k4];
        float4 bb = *(const float4*)&b1[k4];
        v.x = fmaxf(v.x + bb.x, 0.f);
        v.y = fmaxf(v.y + bb.y, 0.f);
        v.z = fmaxf(v.z + bb.z, 0.f);
        v.w = fmaxf(v.w + bb.w, 0.f);
        *(float4*)&As[r][k4] = v;
    }
    __syncthreads();

    int tx = t % 10, ty = t / 10;
    int cb = tx * 4, rb = ty * 4;
    float acc[4][4] = {};
#pragma unroll 2   // capped: full unroll spills (R1)
    for (int k = 0; k < HID; k += 4) {
        float4 xv[4], wv[4];
#pragma unroll
        for (int i = 0; i < 4; i++) xv[i] = *(const float4*)&As[rb + i][k];
#pragma unroll
        for (int kk = 0; kk < 4; kk++) wv[kk] = *(const float4*)&Ws[k + kk][cb];
#pragma unroll
        for (int i = 0; i < 4; i++) {
            const float* xp = (const float*)&xv[i];
#pragma unroll
            for (int kk = 0; kk < 4; kk++) {
                acc[i][0] += xp[kk] * wv[kk].x;
                acc[i][1] += xp[kk] * wv[kk].y;
                acc[i][2] += xp[kk] * wv[kk].z;
                acc[i][3] += xp[kk] * wv[kk].w;
            }
        }
    }
#pragma unroll
    for (int i = 0; i < 4; i++) {
        int gr = row0 + rb + i;
        if (gr < NN)
            *(float4*)&h2[gr * OUTF + cb] =
                make_float4(acc[i][0], acc[i][1], acc[i][2], acc[i][3]);
    }
}

// ---------------- agg2 + bias + log_softmax fused ----------------
__global__ void k_agg2(const int* __restrict__ cursor, const int* __restrict__ eidx,
                       const float* __restrict__ dinv, const float* __restrict__ h2,
                       const float* __restrict__ b2, float* __restrict__ outb) {
    int lane = threadIdx.x & 63;
    int n = (blockIdx.x * blockDim.x + threadIdx.x) >> 6;
    if (n >= NN) return;
    int f = (lane < OUTF) ? lane : (OUTF - 1);  // clamp so all lanes load validly
    int end = cursor[n];
    int start = (n == 0) ? 0 : cursor[n - 1];
    float dn = dinv[n];
    float acc = h2[n * OUTF + f] * dn * dn;  // self-loop
    for (int j = start; j < end; j++) {
        int src = eidx[j];
        float w = dinv[src] * dn;
        acc += h2[src * OUTF + f] * w;
    }
    float v = (lane < OUTF) ? (acc + b2[lane]) : -INFINITY;
    float m = v;
#pragma unroll
    for (int o = 32; o > 0; o >>= 1) m = fmaxf(m, __shfl_xor(m, o, 64));
    float p = (lane < OUTF) ? __expf(v - m) : 0.f;
    float s = p;
#pragma unroll
    for (int o = 32; o > 0; o >>= 1) s += __shfl_xor(s, o, 64);
    if (lane < OUTF) outb[n * OUTF + lane] = v - m - __logf(s);
}

extern "C" void kernel_launch(void* const* d_in, const int* in_sizes, int n_in,
                              void* d_out, int out_size, void* d_ws, size_t ws_size,
                              hipStream_t stream) {
    const float* x  = (const float*)d_in[0];
    const int*   ei = (const int*)d_in[1];
    const float* W1 = (const float*)d_in[2];
    const float* b1 = (const float*)d_in[3];
    const float* W2 = (const float*)d_in[4];
    const float* b2 = (const float*)d_in[5];
    float* outb = (float*)d_out;

    // workspace layout (4B units)
    int*   deg    = (int*)d_ws;                          // 100000
    float* dinv   = (float*)d_ws + 100000;               // 100000
    int*   cursor = (int*)d_ws + 200000;                 // 100000
    int*   bsum   = (int*)d_ws + 300000;                 // 1024
    int*   eidx   = (int*)d_ws + 301024;                 // 1600000
    float* h1     = (float*)d_ws + 1901024;              // 6400000
    float* agg1   = (float*)d_ws + 8301024;              // 6400000
    float* h2     = h1;                                  // reuse (4M < 6.4M)

    k_zero<<<NB, 256, 0, stream>>>(deg);
    k_hist<<<2048, 256, 0, stream>>>(ei + NE, deg);
    k_dinv<<<NB, 256, 0, stream>>>(deg, dinv);
    k_blocksum<<<NB, 256, 0, stream>>>(deg, bsum);
    k_scanbsum<<<1, 512, 0, stream>>>(bsum);
    k_cursor<<<NB, 256, 0, stream>>>(deg, bsum, cursor);
    k_fill<<<2048, 256, 0, stream>>>(ei, cursor, eidx);

    k_gemm1<<<(NN + 63) / 64, 256, 0, stream>>>(x, W1, h1);
    k_agg1<<<(NN * 64 + 255) / 256, 256, 0, stream>>>(cursor, eidx, dinv, h1, agg1);
    k_gemm2<<<(NN + 127) / 128, 320, 0, stream>>>(agg1, b1, W2, h2);
    k_agg2<<<(NN * 64 + 255) / 256, 256, 0, stream>>>(cursor, eidx, dinv, h2, b2, outb);
}

// Round 4
// 391.649 us; speedup vs baseline: 3.5797x; 1.3961x over previous
//
#include <hip/hip_runtime.h>
#include <math.h>

#define NN 100000
#define NE 1600000
#define F_IN 128
#define HID 64
#define OUTF 40
#define NB 391   // (NN+255)/256

__device__ __forceinline__ float4 f4fma(float4 a, float w, float4 acc) {
    acc.x += a.x * w; acc.y += a.y * w; acc.z += a.z * w; acc.w += a.w * w;
    return acc;
}

// ---------------- CSR build ----------------
__global__ void k_zero(int* deg) {
    int i = blockIdx.x * blockDim.x + threadIdx.x;
    if (i < NN) deg[i] = 0;
}

__global__ void k_hist(const int* __restrict__ col, int* __restrict__ deg) {
    int stride = gridDim.x * blockDim.x;
    for (int e = blockIdx.x * blockDim.x + threadIdx.x; e < NE; e += stride)
        atomicAdd(&deg[col[e]], 1);
}

__global__ void k_dinv(const int* __restrict__ deg, float* __restrict__ dinv) {
    int i = blockIdx.x * blockDim.x + threadIdx.x;
    if (i < NN) dinv[i] = rsqrtf((float)(deg[i] + 1));  // +1 self-loop
}

__global__ void k_blocksum(const int* __restrict__ deg, int* __restrict__ bsum) {
    __shared__ int s[256];
    int t = threadIdx.x;
    int i = blockIdx.x * 256 + t;
    s[t] = (i < NN) ? deg[i] : 0;
    __syncthreads();
    for (int o = 128; o > 0; o >>= 1) {
        if (t < o) s[t] += s[t + o];
        __syncthreads();
    }
    if (t == 0) bsum[blockIdx.x] = s[0];
}

__global__ void k_scanbsum(int* __restrict__ bsum) {  // 1 block, 512 threads
    __shared__ int s[512];
    int t = threadIdx.x;
    int v = (t < NB) ? bsum[t] : 0;
    s[t] = v;
    __syncthreads();
    for (int o = 1; o < 512; o <<= 1) {
        int add = (t >= o) ? s[t - o] : 0;
        __syncthreads();
        s[t] += add;
        __syncthreads();
    }
    if (t < NB) bsum[t] = s[t] - v;  // exclusive
}

__global__ void k_cursor(const int* __restrict__ deg, const int* __restrict__ bsum,
                         int* __restrict__ cursor) {
    __shared__ int s[256];
    int t = threadIdx.x;
    int i = blockIdx.x * 256 + t;
    int v = (i < NN) ? deg[i] : 0;
    s[t] = v;
    __syncthreads();
    for (int o = 1; o < 256; o <<= 1) {
        int add = (t >= o) ? s[t - o] : 0;
        __syncthreads();
        s[t] += add;
        __syncthreads();
    }
    if (i < NN) cursor[i] = bsum[blockIdx.x] + s[t] - v;  // exclusive prefix
}

__global__ void k_fill(const int* __restrict__ ei, int* __restrict__ cursor,
                       int* __restrict__ eidx) {
    int stride = gridDim.x * blockDim.x;
    for (int e = blockIdx.x * blockDim.x + threadIdx.x; e < NE; e += stride) {
        int row = ei[e];
        int col = ei[NE + e];
        int pos = atomicAdd(&cursor[col], 1);
        eidx[pos] = row;
    }
    // after: cursor[n] == rowoff[n+1]
}

// ---------------- GEMM1: h1 = x @ W1 ----------------
__launch_bounds__(256)
__global__ void k_gemm1(const float* __restrict__ x, const float* __restrict__ W1,
                        float* __restrict__ h1) {
    __shared__ float Xs[64][132];
    __shared__ float Ws[128][64];
    int t = threadIdx.x;
    int row0 = blockIdx.x * 64;

#pragma unroll
    for (int i = 0; i < 8; i++) {
        int idx4 = t + 256 * i;
        float4 v = ((const float4*)W1)[idx4];
        int k = idx4 >> 4;
        int c4 = (idx4 & 15) << 2;
        *(float4*)&Ws[k][c4] = v;
    }
#pragma unroll
    for (int i = 0; i < 8; i++) {
        int idx4 = t + 256 * i;
        int r = idx4 >> 5;
        int k4 = (idx4 & 31) << 2;
        int gr = row0 + r;
        if (gr >= NN) gr = NN - 1;
        float4 v = *(const float4*)&x[gr * F_IN + k4];
        *(float4*)&Xs[r][k4] = v;
    }
    __syncthreads();

    int tx = t & 15, ty = t >> 4;
    int cb = tx << 2, rb = ty << 2;
    float acc[4][4] = {};
#pragma unroll 2   // capped: full unroll spills (R1)
    for (int k = 0; k < F_IN; k += 4) {
        float4 xv[4], wv[4];
#pragma unroll
        for (int i = 0; i < 4; i++) xv[i] = *(const float4*)&Xs[rb + i][k];
#pragma unroll
        for (int kk = 0; kk < 4; kk++) wv[kk] = *(const float4*)&Ws[k + kk][cb];
#pragma unroll
        for (int i = 0; i < 4; i++) {
            const float* xp = (const float*)&xv[i];
#pragma unroll
            for (int kk = 0; kk < 4; kk++) {
                acc[i][0] += xp[kk] * wv[kk].x;
                acc[i][1] += xp[kk] * wv[kk].y;
                acc[i][2] += xp[kk] * wv[kk].z;
                acc[i][3] += xp[kk] * wv[kk].w;
            }
        }
    }
#pragma unroll
    for (int i = 0; i < 4; i++) {
        int gr = row0 + rb + i;
        if (gr < NN)
            *(float4*)&h1[gr * HID + cb] =
                make_float4(acc[i][0], acc[i][1], acc[i][2], acc[i][3]);
    }
}

// ---------------- aggregation: 4 edge-groups x 16 lanes, float4 rows ----------------
// out[n] = sum_{src in N(n)} h[src]*dinv[src]*dinv[n] + h[n]*dinv[n]^2
// RELU_BIAS: out = relu(out + b)
template <bool RELU_BIAS>
__global__ void k_agg(const int* __restrict__ cursor, const int* __restrict__ eidx,
                      const float* __restrict__ dinv, const float* __restrict__ h,
                      const float* __restrict__ bias, float* __restrict__ outp) {
    int lane = threadIdx.x & 63;
    int n = (blockIdx.x * blockDim.x + threadIdx.x) >> 6;
    if (n >= NN) return;
    int eg = lane >> 4;        // edge group 0..3
    int fq = lane & 15;        // float4 index within 64-float row
    int end = cursor[n];
    int start = (n == 0) ? 0 : cursor[n - 1];
    float dn = dinv[n];

    float4 acc = make_float4(0.f, 0.f, 0.f, 0.f);
    if (eg == 0) {  // self-loop
        float4 hv = *(const float4*)&h[(size_t)n * HID + fq * 4];
        acc = f4fma(hv, dn * dn, acc);
    }
    float4 acc2 = make_float4(0.f, 0.f, 0.f, 0.f);
    int j = start + eg;
    // 2x unroll: 8 independent gathers in flight per wave
    for (; j + 4 < end; j += 8) {
        int s0 = eidx[j];
        int s1 = eidx[j + 4];
        float w0 = dinv[s0] * dn;
        float w1 = dinv[s1] * dn;
        float4 h0 = *(const float4*)&h[(size_t)s0 * HID + fq * 4];
        float4 h1v = *(const float4*)&h[(size_t)s1 * HID + fq * 4];
        acc = f4fma(h0, w0, acc);
        acc2 = f4fma(h1v, w1, acc2);
    }
    if (j < end) {
        int s0 = eidx[j];
        float w0 = dinv[s0] * dn;
        float4 h0 = *(const float4*)&h[(size_t)s0 * HID + fq * 4];
        acc = f4fma(h0, w0, acc);
    }
    acc.x += acc2.x; acc.y += acc2.y; acc.z += acc2.z; acc.w += acc2.w;

    // reduce across the 4 edge groups (lane bits 4,5)
#pragma unroll
    for (int o = 16; o <= 32; o <<= 1) {
        acc.x += __shfl_xor(acc.x, o, 64);
        acc.y += __shfl_xor(acc.y, o, 64);
        acc.z += __shfl_xor(acc.z, o, 64);
        acc.w += __shfl_xor(acc.w, o, 64);
    }
    if (eg == 0) {
        if (RELU_BIAS) {
            float4 bb = *(const float4*)&bias[fq * 4];
            acc.x = fmaxf(acc.x + bb.x, 0.f);
            acc.y = fmaxf(acc.y + bb.y, 0.f);
            acc.z = fmaxf(acc.z + bb.z, 0.f);
            acc.w = fmaxf(acc.w + bb.w, 0.f);
        }
        *(float4*)&outp[(size_t)n * HID + fq * 4] = acc;
    }
}

// ---------------- GEMM2: out = s @ W2 + b2 ----------------
__launch_bounds__(320)
__global__ void k_gemm2(const float* __restrict__ s_in, const float* __restrict__ W2,
                        const float* __restrict__ b2, float* __restrict__ outb) {
    __shared__ float As[128][68];
    __shared__ float Ws[64][40];
    int t = threadIdx.x;
    int row0 = blockIdx.x * 128;

    for (int i = t; i < 64 * 40; i += 320) Ws[i / 40][i % 40] = W2[i];

    for (int idx4 = t; idx4 < 2048; idx4 += 320) {
        int r = idx4 >> 4, k4 = (idx4 & 15) << 2;
        int gr = row0 + r;
        if (gr >= NN) gr = NN - 1;
        *(float4*)&As[r][k4] = *(const float4*)&s_in[(size_t)gr * HID + k4];
    }
    __syncthreads();

    int tx = t % 10, ty = t / 10;
    int cb = tx * 4, rb = ty * 4;
    float acc[4][4] = {};
#pragma unroll 2   // capped: full unroll spills (R1)
    for (int k = 0; k < HID; k += 4) {
        float4 xv[4], wv[4];
#pragma unroll
        for (int i = 0; i < 4; i++) xv[i] = *(const float4*)&As[rb + i][k];
#pragma unroll
        for (int kk = 0; kk < 4; kk++) wv[kk] = *(const float4*)&Ws[k + kk][cb];
#pragma unroll
        for (int i = 0; i < 4; i++) {
            const float* xp = (const float*)&xv[i];
#pragma unroll
            for (int kk = 0; kk < 4; kk++) {
                acc[i][0] += xp[kk] * wv[kk].x;
                acc[i][1] += xp[kk] * wv[kk].y;
                acc[i][2] += xp[kk] * wv[kk].z;
                acc[i][3] += xp[kk] * wv[kk].w;
            }
        }
    }
    float4 bb = *(const float4*)&b2[cb];
#pragma unroll
    for (int i = 0; i < 4; i++) {
        int gr = row0 + rb + i;
        if (gr < NN)
            *(float4*)&outb[(size_t)gr * OUTF + cb] =
                make_float4(acc[i][0] + bb.x, acc[i][1] + bb.y,
                            acc[i][2] + bb.z, acc[i][3] + bb.w);
    }
}

// ---------------- log_softmax in place ----------------
__global__ void k_logsoftmax(float* __restrict__ outb) {
    int lane = threadIdx.x & 63;
    int wid = (blockIdx.x * blockDim.x + threadIdx.x) >> 6;
    if (wid >= NN) return;
    float v = (lane < OUTF) ? outb[(size_t)wid * OUTF + lane] : -INFINITY;
    float m = v;
#pragma unroll
    for (int o = 32; o > 0; o >>= 1) m = fmaxf(m, __shfl_xor(m, o, 64));
    float p = (lane < OUTF) ? __expf(v - m) : 0.f;
    float s = p;
#pragma unroll
    for (int o = 32; o > 0; o >>= 1) s += __shfl_xor(s, o, 64);
    float r = v - m - __logf(s);
    if (lane < OUTF) outb[(size_t)wid * OUTF + lane] = r;
}

extern "C" void kernel_launch(void* const* d_in, const int* in_sizes, int n_in,
                              void* d_out, int out_size, void* d_ws, size_t ws_size,
                              hipStream_t stream) {
    const float* x  = (const float*)d_in[0];
    const int*   ei = (const int*)d_in[1];
    const float* W1 = (const float*)d_in[2];
    const float* b1 = (const float*)d_in[3];
    const float* W2 = (const float*)d_in[4];
    const float* b2 = (const float*)d_in[5];
    float* outb = (float*)d_out;

    // workspace layout (4B units)
    int*   deg    = (int*)d_ws;                 // 100000
    float* dinv   = (float*)d_ws + 100000;      // 100000
    int*   cursor = (int*)d_ws + 200000;        // 100000
    int*   bsum   = (int*)d_ws + 300000;        // 1024
    int*   eidx   = (int*)d_ws + 301056;        // 1600000
    float* h1     = (float*)d_ws + 1901056;     // 6400000 (also reused as s)
    float* r      = (float*)d_ws + 8301056;     // 6400000
    float* s      = h1;                         // h1 dead after agg1

    k_zero<<<NB, 256, 0, stream>>>(deg);
    k_hist<<<2048, 256, 0, stream>>>(ei + NE, deg);
    k_dinv<<<NB, 256, 0, stream>>>(deg, dinv);
    k_blocksum<<<NB, 256, 0, stream>>>(deg, bsum);
    k_scanbsum<<<1, 512, 0, stream>>>(bsum);
    k_cursor<<<NB, 256, 0, stream>>>(deg, bsum, cursor);
    k_fill<<<2048, 256, 0, stream>>>(ei, cursor, eidx);

    k_gemm1<<<(NN + 63) / 64, 256, 0, stream>>>(x, W1, h1);
    // r = relu(A @ h1 + b1)
    k_agg<true><<<(NN * 64 + 255) / 256, 256, 0, stream>>>(cursor, eidx, dinv, h1, b1, r);
    // s = A @ r
    k_agg<false><<<(NN * 64 + 255) / 256, 256, 0, stream>>>(cursor, eidx, dinv, r, nullptr, s);
    // out = s @ W2 + b2, then log_softmax
    k_gemm2<<<(NN + 127) / 128, 320, 0, stream>>>(s, W2, b2, outb);
    k_logsoftmax<<<(NN * 64 + 255) / 256, 256, 0, stream>>>(outb);
}

// Round 5
// 338.727 us; speedup vs baseline: 4.1389x; 1.1562x over previous
//
#include <hip/hip_runtime.h>
#include <math.h>

#define NN 100000
#define NE 1600000
#define F_IN 128
#define HID 64
#define OUTF 40
#define NB 391      // (NN+255)/256
#define NPART 8     // node partitions, one per XCD (blockIdx%8 heuristic)
#define PSIZE 12500 // NN / NPART exactly

__device__ __forceinline__ float4 f4fma(float4 a, float w, float4 acc) {
    acc.x += a.x * w; acc.y += a.y * w; acc.z += a.z * w; acc.w += a.w * w;
    return acc;
}

// ---------------- CSR build ----------------
__global__ void k_zero(int* deg) {
    int i = blockIdx.x * blockDim.x + threadIdx.x;
    if (i < NN) deg[i] = 0;
}

// XCD-partitioned histogram: block p=blockIdx&7 only counts cols in its node
// range -> deg lines stay in ONE XCD's L2 (no cross-XCD line bouncing).
__global__ void k_hist(const int* __restrict__ col, int* __restrict__ deg) {
    int p = blockIdx.x & (NPART - 1);
    int lo = p * PSIZE, hi = lo + PSIZE;
    int tid = (blockIdx.x >> 3) * blockDim.x + threadIdx.x;
    int stride = (gridDim.x >> 3) * blockDim.x;
    for (int e = tid; e < NE; e += stride) {
        int c = col[e];
        if (c >= lo && c < hi) atomicAdd(&deg[c], 1);
    }
}

__global__ void k_dinv(const int* __restrict__ deg, float* __restrict__ dinv) {
    int i = blockIdx.x * blockDim.x + threadIdx.x;
    if (i < NN) dinv[i] = rsqrtf((float)(deg[i] + 1));  // +1 self-loop
}

__global__ void k_blocksum(const int* __restrict__ deg, int* __restrict__ bsum) {
    __shared__ int s[256];
    int t = threadIdx.x;
    int i = blockIdx.x * 256 + t;
    s[t] = (i < NN) ? deg[i] : 0;
    __syncthreads();
    for (int o = 128; o > 0; o >>= 1) {
        if (t < o) s[t] += s[t + o];
        __syncthreads();
    }
    if (t == 0) bsum[blockIdx.x] = s[0];
}

__global__ void k_scanbsum(int* __restrict__ bsum) {  // 1 block, 512 threads
    __shared__ int s[512];
    int t = threadIdx.x;
    int v = (t < NB) ? bsum[t] : 0;
    s[t] = v;
    __syncthreads();
    for (int o = 1; o < 512; o <<= 1) {
        int add = (t >= o) ? s[t - o] : 0;
        __syncthreads();
        s[t] += add;
        __syncthreads();
    }
    if (t < NB) bsum[t] = s[t] - v;  // exclusive
}

__global__ void k_cursor(const int* __restrict__ deg, const int* __restrict__ bsum,
                         int* __restrict__ cursor) {
    __shared__ int s[256];
    int t = threadIdx.x;
    int i = blockIdx.x * 256 + t;
    int v = (i < NN) ? deg[i] : 0;
    s[t] = v;
    __syncthreads();
    for (int o = 1; o < 256; o <<= 1) {
        int add = (t >= o) ? s[t - o] : 0;
        __syncthreads();
        s[t] += add;
        __syncthreads();
    }
    if (i < NN) cursor[i] = bsum[blockIdx.x] + s[t] - v;  // exclusive prefix
}

// XCD-partitioned fill: partition p's cursor atomics AND its contiguous eidx
// slice [rowoff[lo], rowoff[hi]) are written by one XCD only -> lines
// accumulate in local L2, single writeback (R4: was 106MB HBM write for 6.4MB).
__global__ void k_fill(const int* __restrict__ ei, int* __restrict__ cursor,
                       int* __restrict__ eidx) {
    int p = blockIdx.x & (NPART - 1);
    int lo = p * PSIZE, hi = lo + PSIZE;
    int tid = (blockIdx.x >> 3) * blockDim.x + threadIdx.x;
    int stride = (gridDim.x >> 3) * blockDim.x;
    for (int e = tid; e < NE; e += stride) {
        int c = ei[NE + e];
        if (c >= lo && c < hi) {
            int r = ei[e];
            int pos = atomicAdd(&cursor[c], 1);
            eidx[pos] = r;
        }
    }
    // after: cursor[n] == rowoff[n+1]
}

// ---------------- GEMM1: h1 = x @ W1 ----------------
__launch_bounds__(256)
__global__ void k_gemm1(const float* __restrict__ x, const float* __restrict__ W1,
                        float* __restrict__ h1) {
    __shared__ float Xs[64][132];
    __shared__ float Ws[128][64];
    int t = threadIdx.x;
    int row0 = blockIdx.x * 64;

#pragma unroll
    for (int i = 0; i < 8; i++) {
        int idx4 = t + 256 * i;
        float4 v = ((const float4*)W1)[idx4];
        int k = idx4 >> 4;
        int c4 = (idx4 & 15) << 2;
        *(float4*)&Ws[k][c4] = v;
    }
#pragma unroll
    for (int i = 0; i < 8; i++) {
        int idx4 = t + 256 * i;
        int r = idx4 >> 5;
        int k4 = (idx4 & 31) << 2;
        int gr = row0 + r;
        if (gr >= NN) gr = NN - 1;
        float4 v = *(const float4*)&x[gr * F_IN + k4];
        *(float4*)&Xs[r][k4] = v;
    }
    __syncthreads();

    int tx = t & 15, ty = t >> 4;
    int cb = tx << 2, rb = ty << 2;
    float acc[4][4] = {};
#pragma unroll 2   // capped: full unroll spills (R1)
    for (int k = 0; k < F_IN; k += 4) {
        float4 xv[4], wv[4];
#pragma unroll
        for (int i = 0; i < 4; i++) xv[i] = *(const float4*)&Xs[rb + i][k];
#pragma unroll
        for (int kk = 0; kk < 4; kk++) wv[kk] = *(const float4*)&Ws[k + kk][cb];
#pragma unroll
        for (int i = 0; i < 4; i++) {
            const float* xp = (const float*)&xv[i];
#pragma unroll
            for (int kk = 0; kk < 4; kk++) {
                acc[i][0] += xp[kk] * wv[kk].x;
                acc[i][1] += xp[kk] * wv[kk].y;
                acc[i][2] += xp[kk] * wv[kk].z;
                acc[i][3] += xp[kk] * wv[kk].w;
            }
        }
    }
#pragma unroll
    for (int i = 0; i < 4; i++) {
        int gr = row0 + rb + i;
        if (gr < NN)
            *(float4*)&h1[gr * HID + cb] =
                make_float4(acc[i][0], acc[i][1], acc[i][2], acc[i][3]);
    }
}

// ---------------- aggregation: 4 edge-groups x 16 lanes, float4 rows ----------------
template <bool RELU_BIAS>
__global__ void k_agg(const int* __restrict__ cursor, const int* __restrict__ eidx,
                      const float* __restrict__ dinv, const float* __restrict__ h,
                      const float* __restrict__ bias, float* __restrict__ outp) {
    int lane = threadIdx.x & 63;
    int n = (blockIdx.x * blockDim.x + threadIdx.x) >> 6;
    if (n >= NN) return;
    int eg = lane >> 4;        // edge group 0..3
    int fq = lane & 15;        // float4 index within 64-float row
    int end = cursor[n];
    int start = (n == 0) ? 0 : cursor[n - 1];
    float dn = dinv[n];

    float4 acc = make_float4(0.f, 0.f, 0.f, 0.f);
    if (eg == 0) {  // self-loop
        float4 hv = *(const float4*)&h[(size_t)n * HID + fq * 4];
        acc = f4fma(hv, dn * dn, acc);
    }
    float4 acc2 = make_float4(0.f, 0.f, 0.f, 0.f);
    int j = start + eg;
    for (; j + 4 < end; j += 8) {
        int s0 = eidx[j];
        int s1 = eidx[j + 4];
        float w0 = dinv[s0] * dn;
        float w1 = dinv[s1] * dn;
        float4 h0 = *(const float4*)&h[(size_t)s0 * HID + fq * 4];
        float4 h1v = *(const float4*)&h[(size_t)s1 * HID + fq * 4];
        acc = f4fma(h0, w0, acc);
        acc2 = f4fma(h1v, w1, acc2);
    }
    if (j < end) {
        int s0 = eidx[j];
        float w0 = dinv[s0] * dn;
        float4 h0 = *(const float4*)&h[(size_t)s0 * HID + fq * 4];
        acc = f4fma(h0, w0, acc);
    }
    acc.x += acc2.x; acc.y += acc2.y; acc.z += acc2.z; acc.w += acc2.w;

#pragma unroll
    for (int o = 16; o <= 32; o <<= 1) {
        acc.x += __shfl_xor(acc.x, o, 64);
        acc.y += __shfl_xor(acc.y, o, 64);
        acc.z += __shfl_xor(acc.z, o, 64);
        acc.w += __shfl_xor(acc.w, o, 64);
    }
    if (eg == 0) {
        if (RELU_BIAS) {
            float4 bb = *(const float4*)&bias[fq * 4];
            acc.x = fmaxf(acc.x + bb.x, 0.f);
            acc.y = fmaxf(acc.y + bb.y, 0.f);
            acc.z = fmaxf(acc.z + bb.z, 0.f);
            acc.w = fmaxf(acc.w + bb.w, 0.f);
        }
        *(float4*)&outp[(size_t)n * HID + fq * 4] = acc;
    }
}

// ---------------- GEMM2: out = s @ W2 + b2 ----------------
__launch_bounds__(320)
__global__ void k_gemm2(const float* __restrict__ s_in, const float* __restrict__ W2,
                        const float* __restrict__ b2, float* __restrict__ outb) {
    __shared__ float As[128][68];
    __shared__ float Ws[64][40];
    int t = threadIdx.x;
    int row0 = blockIdx.x * 128;

    for (int i = t; i < 64 * 40; i += 320) Ws[i / 40][i % 40] = W2[i];

    for (int idx4 = t; idx4 < 2048; idx4 += 320) {
        int r = idx4 >> 4, k4 = (idx4 & 15) << 2;
        int gr = row0 + r;
        if (gr >= NN) gr = NN - 1;
        *(float4*)&As[r][k4] = *(const float4*)&s_in[(size_t)gr * HID + k4];
    }
    __syncthreads();

    int tx = t % 10, ty = t / 10;
    int cb = tx * 4, rb = ty * 4;
    float acc[4][4] = {};
#pragma unroll 2   // capped: full unroll spills (R1)
    for (int k = 0; k < HID; k += 4) {
        float4 xv[4], wv[4];
#pragma unroll
        for (int i = 0; i < 4; i++) xv[i] = *(const float4*)&As[rb + i][k];
#pragma unroll
        for (int kk = 0; kk < 4; kk++) wv[kk] = *(const float4*)&Ws[k + kk][cb];
#pragma unroll
        for (int i = 0; i < 4; i++) {
            const float* xp = (const float*)&xv[i];
#pragma unroll
            for (int kk = 0; kk < 4; kk++) {
                acc[i][0] += xp[kk] * wv[kk].x;
                acc[i][1] += xp[kk] * wv[kk].y;
                acc[i][2] += xp[kk] * wv[kk].z;
                acc[i][3] += xp[kk] * wv[kk].w;
            }
        }
    }
    float4 bb = *(const float4*)&b2[cb];
#pragma unroll
    for (int i = 0; i < 4; i++) {
        int gr = row0 + rb + i;
        if (gr < NN)
            *(float4*)&outb[(size_t)gr * OUTF + cb] =
                make_float4(acc[i][0] + bb.x, acc[i][1] + bb.y,
                            acc[i][2] + bb.z, acc[i][3] + bb.w);
    }
}

// ---------------- log_softmax in place ----------------
__global__ void k_logsoftmax(float* __restrict__ outb) {
    int lane = threadIdx.x & 63;
    int wid = (blockIdx.x * blockDim.x + threadIdx.x) >> 6;
    if (wid >= NN) return;
    float v = (lane < OUTF) ? outb[(size_t)wid * OUTF + lane] : -INFINITY;
    float m = v;
#pragma unroll
    for (int o = 32; o > 0; o >>= 1) m = fmaxf(m, __shfl_xor(m, o, 64));
    float p = (lane < OUTF) ? __expf(v - m) : 0.f;
    float s = p;
#pragma unroll
    for (int o = 32; o > 0; o >>= 1) s += __shfl_xor(s, o, 64);
    float r = v - m - __logf(s);
    if (lane < OUTF) outb[(size_t)wid * OUTF + lane] = r;
}

extern "C" void kernel_launch(void* const* d_in, const int* in_sizes, int n_in,
                              void* d_out, int out_size, void* d_ws, size_t ws_size,
                              hipStream_t stream) {
    const float* x  = (const float*)d_in[0];
    const int*   ei = (const int*)d_in[1];
    const float* W1 = (const float*)d_in[2];
    const float* b1 = (const float*)d_in[3];
    const float* W2 = (const float*)d_in[4];
    const float* b2 = (const float*)d_in[5];
    float* outb = (float*)d_out;

    // workspace layout (4B units)
    int*   deg    = (int*)d_ws;                 // 100000
    float* dinv   = (float*)d_ws + 100000;      // 100000
    int*   cursor = (int*)d_ws + 200000;        // 100000
    int*   bsum   = (int*)d_ws + 300000;        // 1024
    int*   eidx   = (int*)d_ws + 301056;        // 1600000
    float* h1     = (float*)d_ws + 1901056;     // 6400000 (also reused as s)
    float* r      = (float*)d_ws + 8301056;     // 6400000
    float* s      = h1;                         // h1 dead after agg1

    k_zero<<<NB, 256, 0, stream>>>(deg);
    k_hist<<<2048, 256, 0, stream>>>(ei + NE, deg);
    k_dinv<<<NB, 256, 0, stream>>>(deg, dinv);
    k_blocksum<<<NB, 256, 0, stream>>>(deg, bsum);
    k_scanbsum<<<1, 512, 0, stream>>>(bsum);
    k_cursor<<<NB, 256, 0, stream>>>(deg, bsum, cursor);
    k_fill<<<2048, 256, 0, stream>>>(ei, cursor, eidx);

    k_gemm1<<<(NN + 63) / 64, 256, 0, stream>>>(x, W1, h1);
    // r = relu(A @ h1 + b1)
    k_agg<true><<<(NN * 64 + 255) / 256, 256, 0, stream>>>(cursor, eidx, dinv, h1, b1, r);
    // s = A @ r
    k_agg<false><<<(NN * 64 + 255) / 256, 256, 0, stream>>>(cursor, eidx, dinv, r, nullptr, s);
    // out = s @ W2 + b2, then log_softmax
    k_gemm2<<<(NN + 127) / 128, 320, 0, stream>>>(s, W2, b2, outb);
    k_logsoftmax<<<(NN * 64 + 255) / 256, 256, 0, stream>>>(outb);
}

// Round 6
// 330.225 us; speedup vs baseline: 4.2455x; 1.0257x over previous
//
#include <hip/hip_runtime.h>
#include <math.h>

#define NN 100000
#define NE 1600000
#define F_IN 128
#define HID 64
#define OUTF 40
#define NB 391      // (NN+255)/256
#define NPART 8     // node partitions, one per XCD (blockIdx%8 heuristic)
#define PSIZE 12500 // NN / NPART exactly

typedef unsigned short u16;

__device__ __forceinline__ float bf2f(u16 u) {
    return __uint_as_float(((unsigned int)u) << 16);
}
__device__ __forceinline__ u16 f2bf(float f) {  // RNE
    unsigned int x = __float_as_uint(f);
    return (u16)((x + 0x7fffu + ((x >> 16) & 1u)) >> 16);
}

// ---------------- CSR build ----------------
__global__ void k_zero(int* deg) {
    int i = blockIdx.x * blockDim.x + threadIdx.x;
    if (i < NN) deg[i] = 0;
}

// XCD-partitioned histogram; nt loads keep the edge stream out of L2 so the
// deg lines stay resident (R5: read-stream was evicting dirty lines).
__global__ void k_hist(const int* __restrict__ col, int* __restrict__ deg) {
    int p = blockIdx.x & (NPART - 1);
    int lo = p * PSIZE, hi = lo + PSIZE;
    int tid = (blockIdx.x >> 3) * blockDim.x + threadIdx.x;
    int stride = (gridDim.x >> 3) * blockDim.x;
    for (int e = tid; e < NE; e += stride) {
        int c = __builtin_nontemporal_load(&col[e]);
        if (c >= lo && c < hi) atomicAdd(&deg[c], 1);
    }
}

__global__ void k_dinv(const int* __restrict__ deg, float* __restrict__ dinv) {
    int i = blockIdx.x * blockDim.x + threadIdx.x;
    if (i < NN) dinv[i] = rsqrtf((float)(deg[i] + 1));  // +1 self-loop
}

__global__ void k_blocksum(const int* __restrict__ deg, int* __restrict__ bsum) {
    __shared__ int s[256];
    int t = threadIdx.x;
    int i = blockIdx.x * 256 + t;
    s[t] = (i < NN) ? deg[i] : 0;
    __syncthreads();
    for (int o = 128; o > 0; o >>= 1) {
        if (t < o) s[t] += s[t + o];
        __syncthreads();
    }
    if (t == 0) bsum[blockIdx.x] = s[0];
}

__global__ void k_scanbsum(int* __restrict__ bsum) {  // 1 block, 512 threads
    __shared__ int s[512];
    int t = threadIdx.x;
    int v = (t < NB) ? bsum[t] : 0;
    s[t] = v;
    __syncthreads();
    for (int o = 1; o < 512; o <<= 1) {
        int add = (t >= o) ? s[t - o] : 0;
        __syncthreads();
        s[t] += add;
        __syncthreads();
    }
    if (t < NB) bsum[t] = s[t] - v;  // exclusive
}

__global__ void k_cursor(const int* __restrict__ deg, const int* __restrict__ bsum,
                         int* __restrict__ cursor) {
    __shared__ int s[256];
    int t = threadIdx.x;
    int i = blockIdx.x * 256 + t;
    int v = (i < NN) ? deg[i] : 0;
    s[t] = v;
    __syncthreads();
    for (int o = 1; o < 256; o <<= 1) {
        int add = (t >= o) ? s[t - o] : 0;
        __syncthreads();
        s[t] += add;
        __syncthreads();
    }
    if (i < NN) cursor[i] = bsum[blockIdx.x] + s[t] - v;  // exclusive prefix
}

// XCD-partitioned fill; nt loads on the 8x edge re-read so dirty eidx lines
// fill completely in L2 before a single writeback (R5: WRITE was 73MB/6.4MB).
__global__ void k_fill(const int* __restrict__ ei, int* __restrict__ cursor,
                       int* __restrict__ eidx) {
    int p = blockIdx.x & (NPART - 1);
    int lo = p * PSIZE, hi = lo + PSIZE;
    int tid = (blockIdx.x >> 3) * blockDim.x + threadIdx.x;
    int stride = (gridDim.x >> 3) * blockDim.x;
    for (int e = tid; e < NE; e += stride) {
        int c = __builtin_nontemporal_load(&ei[NE + e]);
        if (c >= lo && c < hi) {
            int r = __builtin_nontemporal_load(&ei[e]);
            int pos = atomicAdd(&cursor[c], 1);
            eidx[pos] = r;
        }
    }
    // after: cursor[n] == rowoff[n+1]
}

// ---------------- GEMM1: h1 = bf16(x @ W1) ----------------
__launch_bounds__(256)
__global__ void k_gemm1(const float* __restrict__ x, const float* __restrict__ W1,
                        u16* __restrict__ h1) {
    __shared__ float Xs[64][132];
    __shared__ float Ws[128][64];
    int t = threadIdx.x;
    int row0 = blockIdx.x * 64;

#pragma unroll
    for (int i = 0; i < 8; i++) {
        int idx4 = t + 256 * i;
        float4 v = ((const float4*)W1)[idx4];
        int k = idx4 >> 4;
        int c4 = (idx4 & 15) << 2;
        *(float4*)&Ws[k][c4] = v;
    }
#pragma unroll
    for (int i = 0; i < 8; i++) {
        int idx4 = t + 256 * i;
        int r = idx4 >> 5;
        int k4 = (idx4 & 31) << 2;
        int gr = row0 + r;
        if (gr >= NN) gr = NN - 1;
        float4 v = *(const float4*)&x[gr * F_IN + k4];
        *(float4*)&Xs[r][k4] = v;
    }
    __syncthreads();

    int tx = t & 15, ty = t >> 4;
    int cb = tx << 2, rb = ty << 2;
    float acc[4][4] = {};
#pragma unroll 2   // capped: full unroll spills (R1)
    for (int k = 0; k < F_IN; k += 4) {
        float4 xv[4], wv[4];
#pragma unroll
        for (int i = 0; i < 4; i++) xv[i] = *(const float4*)&Xs[rb + i][k];
#pragma unroll
        for (int kk = 0; kk < 4; kk++) wv[kk] = *(const float4*)&Ws[k + kk][cb];
#pragma unroll
        for (int i = 0; i < 4; i++) {
            const float* xp = (const float*)&xv[i];
#pragma unroll
            for (int kk = 0; kk < 4; kk++) {
                acc[i][0] += xp[kk] * wv[kk].x;
                acc[i][1] += xp[kk] * wv[kk].y;
                acc[i][2] += xp[kk] * wv[kk].z;
                acc[i][3] += xp[kk] * wv[kk].w;
            }
        }
    }
#pragma unroll
    for (int i = 0; i < 4; i++) {
        int gr = row0 + rb + i;
        if (gr < NN) {
            ushort4 o;
            o.x = f2bf(acc[i][0]); o.y = f2bf(acc[i][1]);
            o.z = f2bf(acc[i][2]); o.w = f2bf(acc[i][3]);
            *(ushort4*)&h1[(size_t)gr * HID + cb] = o;
        }
    }
}

// ---------------- aggregation: bf16 rows, 4 edge-groups x 16 lanes ----------------
// acc += bf16row(src) * w ; fp32 accumulate; output bf16 or fp32
template <bool RELU_BIAS, bool OUT_BF16>
__global__ void k_agg(const int* __restrict__ cursor, const int* __restrict__ eidx,
                      const float* __restrict__ dinv, const u16* __restrict__ h,
                      const float* __restrict__ bias, void* __restrict__ outp) {
    int lane = threadIdx.x & 63;
    int n = (blockIdx.x * blockDim.x + threadIdx.x) >> 6;
    if (n >= NN) return;
    int eg = lane >> 4;        // edge group 0..3
    int fq = lane & 15;        // bf16x4 index within 64-elem row
    int end = cursor[n];
    int start = (n == 0) ? 0 : cursor[n - 1];
    float dn = dinv[n];

    float4 acc = make_float4(0.f, 0.f, 0.f, 0.f);
    if (eg == 0) {  // self-loop
        ushort4 hv = *(const ushort4*)&h[(size_t)n * HID + fq * 4];
        float w = dn * dn;
        acc.x += bf2f(hv.x) * w; acc.y += bf2f(hv.y) * w;
        acc.z += bf2f(hv.z) * w; acc.w += bf2f(hv.w) * w;
    }
    float4 acc2 = make_float4(0.f, 0.f, 0.f, 0.f);
    int j = start + eg;
    for (; j + 4 < end; j += 8) {
        int s0 = eidx[j];
        int s1 = eidx[j + 4];
        float w0 = dinv[s0] * dn;
        float w1 = dinv[s1] * dn;
        ushort4 a = *(const ushort4*)&h[(size_t)s0 * HID + fq * 4];
        ushort4 b = *(const ushort4*)&h[(size_t)s1 * HID + fq * 4];
        acc.x  += bf2f(a.x) * w0; acc.y  += bf2f(a.y) * w0;
        acc.z  += bf2f(a.z) * w0; acc.w  += bf2f(a.w) * w0;
        acc2.x += bf2f(b.x) * w1; acc2.y += bf2f(b.y) * w1;
        acc2.z += bf2f(b.z) * w1; acc2.w += bf2f(b.w) * w1;
    }
    if (j < end) {
        int s0 = eidx[j];
        float w0 = dinv[s0] * dn;
        ushort4 a = *(const ushort4*)&h[(size_t)s0 * HID + fq * 4];
        acc.x += bf2f(a.x) * w0; acc.y += bf2f(a.y) * w0;
        acc.z += bf2f(a.z) * w0; acc.w += bf2f(a.w) * w0;
    }
    acc.x += acc2.x; acc.y += acc2.y; acc.z += acc2.z; acc.w += acc2.w;

#pragma unroll
    for (int o = 16; o <= 32; o <<= 1) {
        acc.x += __shfl_xor(acc.x, o, 64);
        acc.y += __shfl_xor(acc.y, o, 64);
        acc.z += __shfl_xor(acc.z, o, 64);
        acc.w += __shfl_xor(acc.w, o, 64);
    }
    if (eg == 0) {
        if (RELU_BIAS) {
            float4 bb = *(const float4*)&bias[fq * 4];
            acc.x = fmaxf(acc.x + bb.x, 0.f);
            acc.y = fmaxf(acc.y + bb.y, 0.f);
            acc.z = fmaxf(acc.z + bb.z, 0.f);
            acc.w = fmaxf(acc.w + bb.w, 0.f);
        }
        if (OUT_BF16) {
            ushort4 o;
            o.x = f2bf(acc.x); o.y = f2bf(acc.y);
            o.z = f2bf(acc.z); o.w = f2bf(acc.w);
            *(ushort4*)((u16*)outp + (size_t)n * HID + fq * 4) = o;
        } else {
            *(float4*)((float*)outp + (size_t)n * HID + fq * 4) = acc;
        }
    }
}

// ---------------- GEMM2: out = s @ W2 + b2 ----------------
__launch_bounds__(320)
__global__ void k_gemm2(const float* __restrict__ s_in, const float* __restrict__ W2,
                        const float* __restrict__ b2, float* __restrict__ outb) {
    __shared__ float As[128][68];
    __shared__ float Ws[64][40];
    int t = threadIdx.x;
    int row0 = blockIdx.x * 128;

    for (int i = t; i < 64 * 40; i += 320) Ws[i / 40][i % 40] = W2[i];

    for (int idx4 = t; idx4 < 2048; idx4 += 320) {
        int r = idx4 >> 4, k4 = (idx4 & 15) << 2;
        int gr = row0 + r;
        if (gr >= NN) gr = NN - 1;
        *(float4*)&As[r][k4] = *(const float4*)&s_in[(size_t)gr * HID + k4];
    }
    __syncthreads();

    int tx = t % 10, ty = t / 10;
    int cb = tx * 4, rb = ty * 4;
    float acc[4][4] = {};
#pragma unroll 2   // capped: full unroll spills (R1)
    for (int k = 0; k < HID; k += 4) {
        float4 xv[4], wv[4];
#pragma unroll
        for (int i = 0; i < 4; i++) xv[i] = *(const float4*)&As[rb + i][k];
#pragma unroll
        for (int kk = 0; kk < 4; kk++) wv[kk] = *(const float4*)&Ws[k + kk][cb];
#pragma unroll
        for (int i = 0; i < 4; i++) {
            const float* xp = (const float*)&xv[i];
#pragma unroll
            for (int kk = 0; kk < 4; kk++) {
                acc[i][0] += xp[kk] * wv[kk].x;
                acc[i][1] += xp[kk] * wv[kk].y;
                acc[i][2] += xp[kk] * wv[kk].z;
                acc[i][3] += xp[kk] * wv[kk].w;
            }
        }
    }
    float4 bb = *(const float4*)&b2[cb];
#pragma unroll
    for (int i = 0; i < 4; i++) {
        int gr = row0 + rb + i;
        if (gr < NN)
            *(float4*)&outb[(size_t)gr * OUTF + cb] =
                make_float4(acc[i][0] + bb.x, acc[i][1] + bb.y,
                            acc[i][2] + bb.z, acc[i][3] + bb.w);
    }
}

// ---------------- log_softmax in place ----------------
__global__ void k_logsoftmax(float* __restrict__ outb) {
    int lane = threadIdx.x & 63;
    int wid = (blockIdx.x * blockDim.x + threadIdx.x) >> 6;
    if (wid >= NN) return;
    float v = (lane < OUTF) ? outb[(size_t)wid * OUTF + lane] : -INFINITY;
    float m = v;
#pragma unroll
    for (int o = 32; o > 0; o >>= 1) m = fmaxf(m, __shfl_xor(m, o, 64));
    float p = (lane < OUTF) ? __expf(v - m) : 0.f;
    float s = p;
#pragma unroll
    for (int o = 32; o > 0; o >>= 1) s += __shfl_xor(s, o, 64);
    float r = v - m - __logf(s);
    if (lane < OUTF) outb[(size_t)wid * OUTF + lane] = r;
}

extern "C" void kernel_launch(void* const* d_in, const int* in_sizes, int n_in,
                              void* d_out, int out_size, void* d_ws, size_t ws_size,
                              hipStream_t stream) {
    const float* x  = (const float*)d_in[0];
    const int*   ei = (const int*)d_in[1];
    const float* W1 = (const float*)d_in[2];
    const float* b1 = (const float*)d_in[3];
    const float* W2 = (const float*)d_in[4];
    const float* b2 = (const float*)d_in[5];
    float* outb = (float*)d_out;

    // workspace layout (4B word units)
    int*   deg    = (int*)d_ws;                 // 100000
    float* dinv   = (float*)d_ws + 100000;      // 100000
    int*   cursor = (int*)d_ws + 200000;        // 100000
    int*   bsum   = (int*)d_ws + 300000;        // 1024 (+pad)
    int*   eidx   = (int*)d_ws + 301056;        // 1600000
    u16*   h1     = (u16*)((int*)d_ws + 1901056);   // 6.4M bf16 = 3.2M words
    u16*   r      = (u16*)((int*)d_ws + 5101056);   // 6.4M bf16 = 3.2M words
    float* s      = (float*)d_ws + 8301056;     // 6.4M fp32 words

    k_zero<<<NB, 256, 0, stream>>>(deg);
    k_hist<<<2048, 256, 0, stream>>>(ei + NE, deg);
    k_dinv<<<NB, 256, 0, stream>>>(deg, dinv);
    k_blocksum<<<NB, 256, 0, stream>>>(deg, bsum);
    k_scanbsum<<<1, 512, 0, stream>>>(bsum);
    k_cursor<<<NB, 256, 0, stream>>>(deg, bsum, cursor);
    k_fill<<<2048, 256, 0, stream>>>(ei, cursor, eidx);

    k_gemm1<<<(NN + 63) / 64, 256, 0, stream>>>(x, W1, h1);
    // r = bf16(relu(A @ h1 + b1))
    k_agg<true, true><<<(NN * 64 + 255) / 256, 256, 0, stream>>>(cursor, eidx, dinv, h1, b1, r);
    // s = A @ r (fp32)
    k_agg<false, false><<<(NN * 64 + 255) / 256, 256, 0, stream>>>(cursor, eidx, dinv, r, nullptr, s);
    // out = s @ W2 + b2, then log_softmax
    k_gemm2<<<(NN + 127) / 128, 320, 0, stream>>>(s, W2, b2, outb);
    k_logsoftmax<<<(NN * 64 + 255) / 256, 256, 0, stream>>>(outb);
}